// Round 9
// baseline (443.646 us; speedup 1.0000x reference)
//
#include <hip/hip_runtime.h>
#include <hip/hip_bf16.h>
#include <cstdint>
#include <math.h>

// Problem dims
#define BB 8
#define TT 1024
#define CC 768
#define HH 12
#define MROWS (BB*TT)   // 8192

typedef __hip_bfloat16 bf16;
typedef __attribute__((ext_vector_type(8))) __bf16 bf16x8;
typedef __attribute__((ext_vector_type(4))) float f32x4;

#define MFMA16(a,b,c) __builtin_amdgcn_mfma_f32_16x16x32_bf16(a,b,c,0,0,0)

// ---- MFMA fragment-major packed layout -------------------------------------
// P[((m>>4)*Kt32 + (k>>5))*512 + ((m&15) + 16*((k>>3)&3))*8 + (k&7)]
// One fragment = 512 bf16 = 1KB = exactly one wave's A/B operand for
// mfma_f32_16x16x32_bf16 (frag[lane] = M[tile_m*16 + (lane&15)]
//                                       [tile_k*32 + (lane>>4)*8 + e]).
__device__ __forceinline__ void packed_store(bf16* __restrict__ P, int m, int k,
                                             int Kt32, bf16 v) {
  P[((size_t)(m >> 4) * Kt32 + (k >> 5)) * 512 +
    ((m & 15) + 16 * ((k >> 3) & 3)) * 8 + (k & 7)] = v;
}

// ---------------- LayerNorm: f32 [rows][768] -> bf16 packed-A ---------------
__global__ __launch_bounds__(256) void ln_pack_kernel(
    const float* __restrict__ x, const float* __restrict__ scale,
    const float* __restrict__ bias, bf16* __restrict__ out)
{
  int row = blockIdx.x;
  const float* xr = x + (size_t)row * CC;
  float v[3];
  float s = 0.f, s2 = 0.f;
  for (int i = 0; i < 3; i++) {
    v[i] = xr[threadIdx.x + i*256];
    s += v[i]; s2 += v[i]*v[i];
  }
  for (int m = 1; m < 64; m <<= 1) { s += __shfl_xor(s, m); s2 += __shfl_xor(s2, m); }
  __shared__ float ssum[4], ssum2[4];
  int w = threadIdx.x >> 6;
  if ((threadIdx.x & 63) == 0) { ssum[w] = s; ssum2[w] = s2; }
  __syncthreads();
  s = ssum[0]+ssum[1]+ssum[2]+ssum[3];
  s2 = ssum2[0]+ssum2[1]+ssum2[2]+ssum2[3];
  float mu = s * (1.f/CC);
  float var = s2 * (1.f/CC) - mu*mu;
  float rs = rsqrtf(var + 1e-5f);
  for (int i = 0; i < 3; i++) {
    int c = threadIdx.x + i*256;
    packed_store(out, row, c, CC/32,
                 __float2bfloat16((v[i]-mu)*rs*scale[c] + bias[c]));
  }
}

// ------- weight pack: src f32 [K][N] -> packed B-frags over Bt[N][K] --------
// grid (N/16, K/128), block 256: 4 fragments per block.
__global__ __launch_bounds__(256) void wpack_kernel(
    const float* __restrict__ src, bf16* __restrict__ dst, int K, int N)
{
  int lane = threadIdx.x & 63;
  int kt = blockIdx.y*4 + (threadIdx.x >> 6);
  int nt = blockIdx.x;
  int Kt = K >> 5;
  int n = nt*16 + (lane & 15);
  int k0 = kt*32 + (lane >> 4)*8;
  bf16 vals[8];
  for (int e = 0; e < 8; e++)
    vals[e] = __float2bfloat16(src[(size_t)(k0 + e)*N + n]);
  *reinterpret_cast<bf16x8*>(dst + ((size_t)nt*Kt + kt)*512 + lane*8) =
      *reinterpret_cast<bf16x8*>(vals);
}

// ------------- V transpose: [BH][T][64] -> [BH][64][T] (bf16) -------------
__global__ __launch_bounds__(256) void vtrans_kernel(
    const bf16* __restrict__ src, bf16* __restrict__ dst)
{
  __shared__ bf16 tile[64][65];
  int bh = blockIdx.x >> 4, t0 = (blockIdx.x & 15) * 64;
  const bf16* s = src + ((size_t)bh * TT + t0) * 64;
  for (int i = 0; i < 16; i++) {
    int idx = threadIdx.x + i*256;
    tile[idx >> 6][idx & 63] = s[idx];
  }
  __syncthreads();
  bf16* o = dst + (size_t)bh * 64 * TT + t0;
  for (int i = 0; i < 16; i++) {
    int idx = threadIdx.x + i*256;
    int d = idx >> 6, t = idx & 63;
    o[(size_t)d * TT + t] = tile[t][d];
  }
}

// ------------- GEMM on packed fragments: LDS-free, barrier-free -------------
// A packed [Mt][Kt] frags, B packed [Nt][Kt] frags. Per wave: 4 m-tiles x
// 4 n-tiles, K-loop loads 8 coalesced 1KB fragments/iter directly from
// global (L2-resident panels, XCD band swizzle) with register ping-pong
// prefetch (Kt even). No __shared__, no __syncthreads.
// EPI 0: qkv scatter -> Q,K,V bf16 [B,H,T,64]
// EPI 1: f32 out = acc + bias + res (row-major)
// EPI 2: gelu(acc+bias) -> bf16 packed-A layout (for next GEMM)
template<int EPI>
__global__ __launch_bounds__(256) void gemm_pk(
    const bf16* __restrict__ A, const bf16* __restrict__ B,
    const float* __restrict__ bias, int Ndim, int Kdim,
    const float* __restrict__ res, void* __restrict__ out0,
    bf16* __restrict__ outK, bf16* __restrict__ outV)
{
  int tid = threadIdx.x;
  int wave = tid >> 6, lane = tid & 63;
  int quad = lane >> 4, l15 = lane & 15;
  int wr = wave >> 1, wc = wave & 1;

  int Nb = gridDim.x;
  int lin = blockIdx.y * Nb + blockIdx.x;
  int band = lin / (8*Nb);
  int rem  = lin - band*8*Nb;
  int m0 = (band*8 + (rem & 7)) * 128;
  int n0 = (rem >> 3) * 128;

  const int Kt = Kdim >> 5;
  const bf16* baseA[4];
  const bf16* baseB[4];
  for (int i = 0; i < 4; i++)
    baseA[i] = A + (size_t)((m0 >> 4) + wr*4 + i) * Kt * 512;
  for (int j = 0; j < 4; j++)
    baseB[j] = B + (size_t)((n0 >> 4) + wc*4 + j) * Kt * 512;

  f32x4 acc[4][4];
  for (int i = 0; i < 4; i++) for (int j = 0; j < 4; j++)
    acc[i][j] = (f32x4){0.f,0.f,0.f,0.f};

  size_t voff = (size_t)lane * 8;
  bf16x8 ca[4], cb[4], na[4], nb[4];
  for (int i = 0; i < 4; i++) ca[i] = *reinterpret_cast<const bf16x8*>(baseA[i] + voff);
  for (int j = 0; j < 4; j++) cb[j] = *reinterpret_cast<const bf16x8*>(baseB[j] + voff);

  for (int kt = 0; kt < Kt; kt += 2) {
    // prefetch kt+1 (always exists: Kt even)
    for (int i = 0; i < 4; i++) na[i] = *reinterpret_cast<const bf16x8*>(baseA[i] + voff + 512);
    for (int j = 0; j < 4; j++) nb[j] = *reinterpret_cast<const bf16x8*>(baseB[j] + voff + 512);
    for (int i = 0; i < 4; i++)
      for (int j = 0; j < 4; j++)
        acc[i][j] = MFMA16(ca[i], cb[j], acc[i][j]);
    if (kt + 2 < Kt) {   // prefetch kt+2
      for (int i = 0; i < 4; i++) ca[i] = *reinterpret_cast<const bf16x8*>(baseA[i] + voff + 1024);
      for (int j = 0; j < 4; j++) cb[j] = *reinterpret_cast<const bf16x8*>(baseB[j] + voff + 1024);
    }
    for (int i = 0; i < 4; i++)
      for (int j = 0; j < 4; j++)
        acc[i][j] = MFMA16(na[i], nb[j], acc[i][j]);
    voff += 1024;
  }

  for (int i = 0; i < 4; i++) {
    for (int j = 0; j < 4; j++) {
      for (int r = 0; r < 4; r++) {
        int row = m0 + wr*64 + i*16 + quad*4 + r;
        int col = n0 + wc*64 + j*16 + l15;
        float cv = acc[i][j][r] + bias[col];
        if (EPI == 0) {
          int part = col / 768;
          int cc = col - part*768;
          int h = cc >> 6, d = cc & 63;
          int b = row >> 10, t = row & 1023;
          bf16* dst = (part == 0) ? (bf16*)out0 : (part == 1) ? outK : outV;
          dst[(((size_t)(b*HH + h))*TT + t)*64 + d] = __float2bfloat16(cv);
        } else if (EPI == 1) {
          ((float*)out0)[(size_t)row*Ndim + col] = cv + res[(size_t)row*Ndim + col];
        } else {
          float u = cv;
          float y = 0.7978845608f*(u + 0.044715f*u*u*u);
          float e = __expf(2.f*fabsf(y));
          float z = 2.f/(e + 1.f);                  // 1 - tanh(|y|)
          float sel = (y >= 0.f) ? (2.f - z) : z;   // 1 + tanh(y)
          packed_store((bf16*)out0, row, col, Ndim >> 5,
                       __float2bfloat16(0.5f*u*sel));
        }
      }
    }
  }
}

// ------------- flash attention with LDS-staged K/V -------------
// Output ctx written in packed-A layout for the attnproj GEMM.
__global__ __launch_bounds__(256) void attn_kernel(
    const bf16* __restrict__ Q, const bf16* __restrict__ Kb,
    const bf16* __restrict__ Vt, bf16* __restrict__ ctx)
{
  __shared__ bf16 Ks[64*64];      // [key][d], swizzled
  __shared__ bf16 Vs[64*64];      // [d][key], swizzled
  __shared__ bf16 Ps[4*16*64];    // per-wave [q][key], q-swizzled

  int tid = threadIdx.x, wave = tid >> 6, lane = tid & 63;
  int quad = lane >> 4, l15 = lane & 15;
  int bh = blockIdx.x >> 4;
  int tile = 15 - (blockIdx.x & 15);          // heavy tiles first
  int q0b = tile*64;
  int q0w = q0b + wave*16;
  int b = bh / HH, h = bh - b*HH;
  const bf16* Qp = Q + ((size_t)bh*TT + q0w)*64;
  const bf16* Kp = Kb + (size_t)bh*TT*64;
  const bf16* Vp = Vt + (size_t)bh*64*TT;
  bf16* Pw = Ps + wave*16*64;

  bf16x8 qf[2];
  qf[0] = *reinterpret_cast<const bf16x8*>(Qp + l15*64 + quad*8);
  qf[1] = *reinterpret_cast<const bf16x8*>(Qp + l15*64 + 32 + quad*8);

  f32x4 O[4];
  for (int j = 0; j < 4; j++) O[j] = (f32x4){0.f,0.f,0.f,0.f};
  float lsum[4] = {0.f, 0.f, 0.f, 0.f};
  const float c2 = 0.18033688f;   // (1/8) * log2(e)

  const int srow0 = wave*16 + (lane >> 3);   // + rep*8
  const int sc    = lane & 7;                // 16B block within 128B row

  int nc = tile + 1;               // number of 64-key chunks

  bf16x8 kreg[2], vreg[2], kreg2[2], vreg2[2];
  for (int rep = 0; rep < 2; rep++) {
    int row = srow0 + rep*8;
    kreg[rep] = *reinterpret_cast<const bf16x8*>(Kp + (size_t)row*64 + sc*8);
    vreg[rep] = *reinterpret_cast<const bf16x8*>(Vp + (size_t)row*TT + sc*8);
  }

  for (int ci = 0; ci < nc; ci++) {
    int kbase = ci*64;
    __syncthreads();
    for (int rep = 0; rep < 2; rep++) {
      int row = srow0 + rep*8;
      int ph = sc ^ (row & 7);
      *reinterpret_cast<bf16x8*>(Ks + row*64 + ph*8) = kreg[rep];
      *reinterpret_cast<bf16x8*>(Vs + row*64 + ph*8) = vreg[rep];
    }
    if (ci + 1 < nc) {
      int kb2 = kbase + 64;
      for (int rep = 0; rep < 2; rep++) {
        int row = srow0 + rep*8;
        kreg2[rep] = *reinterpret_cast<const bf16x8*>(Kp + (size_t)(kb2 + row)*64 + sc*8);
        vreg2[rep] = *reinterpret_cast<const bf16x8*>(Vp + (size_t)row*TT + kb2 + sc*8);
      }
    }
    __syncthreads();

    f32x4 S[4];
    for (int j = 0; j < 4; j++) S[j] = (f32x4){0.f,0.f,0.f,0.f};
    for (int kh = 0; kh < 2; kh++) {
      for (int j = 0; j < 4; j++) {
        int key = j*16 + l15;
        bf16x8 kf = *reinterpret_cast<const bf16x8*>(
            Ks + key*64 + ((kh*4 + quad) ^ (key & 7))*8);
        S[j] = MFMA16(qf[kh], kf, S[j]);
      }
    }

    float p[4][4];
    if (kbase + 63 > q0w) {
      for (int j = 0; j < 4; j++) {
        int key = kbase + j*16 + l15;
        for (int r = 0; r < 4; r++) {
          int row = q0w + quad*4 + r;
          p[j][r] = (key <= row) ? __builtin_amdgcn_exp2f(S[j][r]*c2) : 0.f;
        }
      }
    } else {
      for (int j = 0; j < 4; j++)
        for (int r = 0; r < 4; r++)
          p[j][r] = __builtin_amdgcn_exp2f(S[j][r]*c2);
    }
    for (int j = 0; j < 4; j++)
      for (int r = 0; r < 4; r++) lsum[r] += p[j][r];

    for (int j = 0; j < 4; j++) {
      int cblk = j*2 + (l15 >> 3);
      int koff = l15 & 7;
      for (int r = 0; r < 4; r++) {
        int q = quad*4 + r;
        Pw[q*64 + (cblk ^ (q & 7))*8 + koff] = __float2bfloat16(p[j][r]);
      }
    }

    for (int kh = 0; kh < 2; kh++) {
      bf16x8 pf = *reinterpret_cast<const bf16x8*>(
          Pw + l15*64 + ((kh*4 + quad) ^ (l15 & 7))*8);
      for (int j = 0; j < 4; j++) {
        int d = j*16 + l15;
        bf16x8 vf = *reinterpret_cast<const bf16x8*>(
            Vs + d*64 + ((kh*4 + quad) ^ (d & 7))*8);
        O[j] = MFMA16(pf, vf, O[j]);
      }
    }

    for (int rep = 0; rep < 2; rep++) { kreg[rep] = kreg2[rep]; vreg[rep] = vreg2[rep]; }
  }

  for (int r = 0; r < 4; r++)
    for (int msk = 1; msk < 16; msk <<= 1)
      lsum[r] += __shfl_xor(lsum[r], msk);

  // packed-A write of ctx: m = global row, k = h*64 + j*16 + l15
  for (int r = 0; r < 4; r++) {
    float inv = 1.f / lsum[r];
    int m = b*TT + q0w + quad*4 + r;
    for (int j = 0; j < 4; j++)
      packed_store(ctx, m, h*64 + j*16 + l15, CC/32,
                   __float2bfloat16(O[j][r]*inv));
  }
}

extern "C" void kernel_launch(void* const* d_in, const int* in_sizes, int n_in,
                              void* d_out, int out_size, void* d_ws, size_t ws_size,
                              hipStream_t stream)
{
  const float* x    = (const float*)d_in[0];
  const float* ln1s = (const float*)d_in[2];
  const float* ln1b = (const float*)d_in[3];
  const float* wqkv = (const float*)d_in[4];
  const float* bqkv = (const float*)d_in[5];
  const float* wap  = (const float*)d_in[6];
  const float* bap  = (const float*)d_in[7];
  const float* ln2s = (const float*)d_in[8];
  const float* ln2b = (const float*)d_in[9];
  const float* wfc  = (const float*)d_in[10];
  const float* bfc  = (const float*)d_in[11];
  const float* wmp  = (const float*)d_in[12];
  const float* bmp  = (const float*)d_in[13];

  char* ws = (char*)d_ws;
  bf16* wqkv_t = (bf16*)ws; ws += (size_t)2304*768*2;
  bf16* wap_t  = (bf16*)ws; ws += (size_t)768*768*2;
  bf16* wfc_t  = (bf16*)ws; ws += (size_t)3072*768*2;
  bf16* wmp_t  = (bf16*)ws; ws += (size_t)768*3072*2;
  bf16* buf1   = (bf16*)ws; ws += (size_t)MROWS*CC*2;   // packed: h / ctx / h2
  bf16* Qb     = (bf16*)ws; ws += (size_t)MROWS*CC*2;
  bf16* Kbuf   = (bf16*)ws; ws += (size_t)MROWS*CC*2;
  bf16* Vb     = (bf16*)ws; ws += (size_t)MROWS*CC*2;
  bf16* Vt     = (bf16*)ws; ws += (size_t)MROWS*CC*2;
  bf16* g      = Qb;  // reuse Q/K/V/Vt region for packed [8192][3072] bf16
  float* r1    = (float*)ws; ws += (size_t)MROWS*CC*4;

  dim3 blk(256);
  // weight packs (fragment-major)
  wpack_kernel<<<dim3(2304/16, 768/128), blk, 0, stream>>>(wqkv, wqkv_t, 768, 2304);
  wpack_kernel<<<dim3(768/16, 768/128), blk, 0, stream>>>(wap, wap_t, 768, 768);
  wpack_kernel<<<dim3(3072/16, 768/128), blk, 0, stream>>>(wfc, wfc_t, 768, 3072);
  wpack_kernel<<<dim3(768/16, 3072/128), blk, 0, stream>>>(wmp, wmp_t, 3072, 768);
  // LN1 -> packed h
  ln_pack_kernel<<<MROWS, blk, 0, stream>>>(x, ln1s, ln1b, buf1);
  // QKV GEMM -> Q,K,V row-major [B,H,T,64]
  gemm_pk<0><<<dim3(2304/128, MROWS/128), blk, 0, stream>>>(
      buf1, wqkv_t, bqkv, 2304, 768, nullptr, (void*)Qb, Kbuf, Vb);
  vtrans_kernel<<<BB*HH*16, blk, 0, stream>>>(Vb, Vt);
  // attention -> packed ctx
  attn_kernel<<<BB*HH*16, blk, 0, stream>>>(Qb, Kbuf, Vt, buf1);
  // attn proj + residual -> r1 (f32 row-major)
  gemm_pk<1><<<dim3(768/128, MROWS/128), blk, 0, stream>>>(
      buf1, wap_t, bap, 768, 768, x, (void*)r1, nullptr, nullptr);
  // LN2 -> packed h2
  ln_pack_kernel<<<MROWS, blk, 0, stream>>>(r1, ln2s, ln2b, buf1);
  // fc + gelu -> packed g
  gemm_pk<2><<<dim3(3072/128, MROWS/128), blk, 0, stream>>>(
      buf1, wfc_t, bfc, 3072, 768, nullptr, (void*)g, nullptr, nullptr);
  // mlp proj + residual -> out (f32 row-major)
  gemm_pk<1><<<dim3(768/128, MROWS/128), blk, 0, stream>>>(
      g, wmp_t, bmp, 768, 3072, r1, d_out, nullptr, nullptr);
}

// Round 10
// 411.476 us; speedup vs baseline: 1.0782x; 1.0782x over previous
//
#include <hip/hip_runtime.h>
#include <hip/hip_bf16.h>
#include <cstdint>
#include <math.h>

// Problem dims
#define BB 8
#define TT 1024
#define CC 768
#define HH 12
#define MROWS (BB*TT)   // 8192

typedef __hip_bfloat16 bf16;
typedef __attribute__((ext_vector_type(8))) __bf16 bf16x8;
typedef __attribute__((ext_vector_type(4))) float f32x4;

#define MFMA16(a,b,c) __builtin_amdgcn_mfma_f32_16x16x32_bf16(a,b,c,0,0,0)

// ---- MFMA fragment-major packed layout -------------------------------------
// P[((m>>4)*Kt32 + (k>>5))*512 + ((m&15) + 16*((k>>3)&3))*8 + (k&7)]
__device__ __forceinline__ void packed_store(bf16* __restrict__ P, int m, int k,
                                             int Kt32, bf16 v) {
  P[((size_t)(m >> 4) * Kt32 + (k >> 5)) * 512 +
    ((m & 15) + 16 * ((k >> 3) & 3)) * 8 + (k & 7)] = v;
}

// ---------------- LayerNorm: f32 [rows][768] -> bf16 packed-A ---------------
__global__ __launch_bounds__(256) void ln_pack_kernel(
    const float* __restrict__ x, const float* __restrict__ scale,
    const float* __restrict__ bias, bf16* __restrict__ out)
{
  int row = blockIdx.x;
  const float* xr = x + (size_t)row * CC;
  float v[3];
  float s = 0.f, s2 = 0.f;
  for (int i = 0; i < 3; i++) {
    v[i] = xr[threadIdx.x + i*256];
    s += v[i]; s2 += v[i]*v[i];
  }
  for (int m = 1; m < 64; m <<= 1) { s += __shfl_xor(s, m); s2 += __shfl_xor(s2, m); }
  __shared__ float ssum[4], ssum2[4];
  int w = threadIdx.x >> 6;
  if ((threadIdx.x & 63) == 0) { ssum[w] = s; ssum2[w] = s2; }
  __syncthreads();
  s = ssum[0]+ssum[1]+ssum[2]+ssum[3];
  s2 = ssum2[0]+ssum2[1]+ssum2[2]+ssum2[3];
  float mu = s * (1.f/CC);
  float var = s2 * (1.f/CC) - mu*mu;
  float rs = rsqrtf(var + 1e-5f);
  for (int i = 0; i < 3; i++) {
    int c = threadIdx.x + i*256;
    packed_store(out, row, c, CC/32,
                 __float2bfloat16((v[i]-mu)*rs*scale[c] + bias[c]));
  }
}

// ------- weight pack: src f32 [K][N] -> packed B-frags over Bt[N][K] --------
__global__ __launch_bounds__(256) void wpack_kernel(
    const float* __restrict__ src, bf16* __restrict__ dst, int K, int N)
{
  int lane = threadIdx.x & 63;
  int kt = blockIdx.y*4 + (threadIdx.x >> 6);
  int nt = blockIdx.x;
  int Kt = K >> 5;
  int n = nt*16 + (lane & 15);
  int k0 = kt*32 + (lane >> 4)*8;
  bf16 vals[8];
  for (int e = 0; e < 8; e++)
    vals[e] = __float2bfloat16(src[(size_t)(k0 + e)*N + n]);
  *reinterpret_cast<bf16x8*>(dst + ((size_t)nt*Kt + kt)*512 + lane*8) =
      *reinterpret_cast<bf16x8*>(vals);
}

// ------------- V transpose: [BH][T][64] -> [BH][64][T] (bf16) -------------
__global__ __launch_bounds__(256) void vtrans_kernel(
    const bf16* __restrict__ src, bf16* __restrict__ dst)
{
  __shared__ bf16 tile[64][65];
  int bh = blockIdx.x >> 4, t0 = (blockIdx.x & 15) * 64;
  const bf16* s = src + ((size_t)bh * TT + t0) * 64;
  for (int i = 0; i < 16; i++) {
    int idx = threadIdx.x + i*256;
    tile[idx >> 6][idx & 63] = s[idx];
  }
  __syncthreads();
  bf16* o = dst + (size_t)bh * 64 * TT + t0;
  for (int i = 0; i < 16; i++) {
    int idx = threadIdx.x + i*256;
    int d = idx >> 6, t = idx & 63;
    o[(size_t)d * TT + t] = tile[t][d];
  }
}

// --------- GEMM on packed fragments: LDS-free, high-intensity tiles ---------
// Block 256x128 (M x N), 4 waves split M: wave tile 64x128.
// Per wave-iter: 4 private A-frags + 8 shared B-frags (L1 dedups across
// waves) -> 32 MFMAs (2.67 MFMA per 1KB fragment read vs 2.0 at 64x64).
// Register ping-pong prefetch, no LDS, no barriers. XCD band swizzle.
template<int EPI>
__global__ __launch_bounds__(256, 2) void gemm_pk(
    const bf16* __restrict__ A, const bf16* __restrict__ B,
    const float* __restrict__ bias, int Ndim, int Kdim,
    const float* __restrict__ res, void* __restrict__ out0,
    bf16* __restrict__ outK, bf16* __restrict__ outV)
{
  int tid = threadIdx.x;
  // force wave index scalar so frag bases live in SGPRs (saddr+voff loads)
  int wave = __builtin_amdgcn_readfirstlane(tid >> 6);
  int lane = tid & 63;
  int quad = lane >> 4, l15 = lane & 15;

  int Nb = gridDim.x;
  int lin = blockIdx.y * Nb + blockIdx.x;
  int band = lin / (8*Nb);
  int rem  = lin - band*8*Nb;
  int m0 = (band*8 + (rem & 7)) * 256;
  int n0 = (rem >> 3) * 128;

  const int Kt = Kdim >> 5;
  const bf16* Abase = A + (size_t)((m0 >> 4) + wave*4) * Kt * 512;
  const bf16* Bbase = B + (size_t)(n0 >> 4) * Kt * 512;
  const size_t fstep = (size_t)Kt * 512;   // frag-row stride

  f32x4 acc[4][8];
  for (int i = 0; i < 4; i++) for (int j = 0; j < 8; j++)
    acc[i][j] = (f32x4){0.f,0.f,0.f,0.f};

  size_t voff = (size_t)lane * 8;
  bf16x8 ca[4], cb[8], na[4], nb[8];
  for (int i = 0; i < 4; i++) ca[i] = *reinterpret_cast<const bf16x8*>(Abase + i*fstep + voff);
  for (int j = 0; j < 8; j++) cb[j] = *reinterpret_cast<const bf16x8*>(Bbase + j*fstep + voff);

  for (int kt = 0; kt < Kt; kt += 2) {
    // prefetch kt+1 (Kt always even here)
    for (int i = 0; i < 4; i++) na[i] = *reinterpret_cast<const bf16x8*>(Abase + i*fstep + voff + 512);
    for (int j = 0; j < 8; j++) nb[j] = *reinterpret_cast<const bf16x8*>(Bbase + j*fstep + voff + 512);
    for (int i = 0; i < 4; i++)
      for (int j = 0; j < 8; j++)
        acc[i][j] = MFMA16(ca[i], cb[j], acc[i][j]);
    if (kt + 2 < Kt) {
      for (int i = 0; i < 4; i++) ca[i] = *reinterpret_cast<const bf16x8*>(Abase + i*fstep + voff + 1024);
      for (int j = 0; j < 8; j++) cb[j] = *reinterpret_cast<const bf16x8*>(Bbase + j*fstep + voff + 1024);
    }
    for (int i = 0; i < 4; i++)
      for (int j = 0; j < 8; j++)
        acc[i][j] = MFMA16(na[i], nb[j], acc[i][j]);
    voff += 1024;
  }

  for (int i = 0; i < 4; i++) {
    for (int j = 0; j < 8; j++) {
      for (int r = 0; r < 4; r++) {
        int row = m0 + wave*64 + i*16 + quad*4 + r;
        int col = n0 + j*16 + l15;
        float cv = acc[i][j][r] + bias[col];
        if (EPI == 0) {
          int part = col / 768;
          int cc = col - part*768;
          int h = cc >> 6, d = cc & 63;
          int b = row >> 10, t = row & 1023;
          bf16* dst = (part == 0) ? (bf16*)out0 : (part == 1) ? outK : outV;
          dst[(((size_t)(b*HH + h))*TT + t)*64 + d] = __float2bfloat16(cv);
        } else if (EPI == 1) {
          ((float*)out0)[(size_t)row*Ndim + col] = cv + res[(size_t)row*Ndim + col];
        } else {
          float u = cv;
          float y = 0.7978845608f*(u + 0.044715f*u*u*u);
          float e = __expf(2.f*fabsf(y));
          float z = 2.f/(e + 1.f);                  // 1 - tanh(|y|)
          float sel = (y >= 0.f) ? (2.f - z) : z;   // 1 + tanh(y)
          packed_store((bf16*)out0, row, col, Ndim >> 5,
                       __float2bfloat16(0.5f*u*sel));
        }
      }
    }
  }
}

// ------------- flash attention with LDS-staged K/V -------------
__global__ __launch_bounds__(256) void attn_kernel(
    const bf16* __restrict__ Q, const bf16* __restrict__ Kb,
    const bf16* __restrict__ Vt, bf16* __restrict__ ctx)
{
  __shared__ bf16 Ks[64*64];      // [key][d], swizzled
  __shared__ bf16 Vs[64*64];      // [d][key], swizzled
  __shared__ bf16 Ps[4*16*64];    // per-wave [q][key], q-swizzled

  int tid = threadIdx.x, wave = tid >> 6, lane = tid & 63;
  int quad = lane >> 4, l15 = lane & 15;
  int bh = blockIdx.x >> 4;
  int tile = 15 - (blockIdx.x & 15);          // heavy tiles first
  int q0b = tile*64;
  int q0w = q0b + wave*16;
  int b = bh / HH, h = bh - b*HH;
  const bf16* Qp = Q + ((size_t)bh*TT + q0w)*64;
  const bf16* Kp = Kb + (size_t)bh*TT*64;
  const bf16* Vp = Vt + (size_t)bh*64*TT;
  bf16* Pw = Ps + wave*16*64;

  bf16x8 qf[2];
  qf[0] = *reinterpret_cast<const bf16x8*>(Qp + l15*64 + quad*8);
  qf[1] = *reinterpret_cast<const bf16x8*>(Qp + l15*64 + 32 + quad*8);

  f32x4 O[4];
  for (int j = 0; j < 4; j++) O[j] = (f32x4){0.f,0.f,0.f,0.f};
  float lsum[4] = {0.f, 0.f, 0.f, 0.f};
  const float c2 = 0.18033688f;   // (1/8) * log2(e)

  const int srow0 = wave*16 + (lane >> 3);   // + rep*8
  const int sc    = lane & 7;                // 16B block within 128B row

  int nc = tile + 1;               // number of 64-key chunks

  bf16x8 kreg[2], vreg[2], kreg2[2], vreg2[2];
  for (int rep = 0; rep < 2; rep++) {
    int row = srow0 + rep*8;
    kreg[rep] = *reinterpret_cast<const bf16x8*>(Kp + (size_t)row*64 + sc*8);
    vreg[rep] = *reinterpret_cast<const bf16x8*>(Vp + (size_t)row*TT + sc*8);
  }

  for (int ci = 0; ci < nc; ci++) {
    int kbase = ci*64;
    __syncthreads();
    for (int rep = 0; rep < 2; rep++) {
      int row = srow0 + rep*8;
      int ph = sc ^ (row & 7);
      *reinterpret_cast<bf16x8*>(Ks + row*64 + ph*8) = kreg[rep];
      *reinterpret_cast<bf16x8*>(Vs + row*64 + ph*8) = vreg[rep];
    }
    if (ci + 1 < nc) {
      int kb2 = kbase + 64;
      for (int rep = 0; rep < 2; rep++) {
        int row = srow0 + rep*8;
        kreg2[rep] = *reinterpret_cast<const bf16x8*>(Kp + (size_t)(kb2 + row)*64 + sc*8);
        vreg2[rep] = *reinterpret_cast<const bf16x8*>(Vp + (size_t)row*TT + kb2 + sc*8);
      }
    }
    __syncthreads();

    f32x4 S[4];
    for (int j = 0; j < 4; j++) S[j] = (f32x4){0.f,0.f,0.f,0.f};
    for (int kh = 0; kh < 2; kh++) {
      for (int j = 0; j < 4; j++) {
        int key = j*16 + l15;
        bf16x8 kf = *reinterpret_cast<const bf16x8*>(
            Ks + key*64 + ((kh*4 + quad) ^ (key & 7))*8);
        S[j] = MFMA16(qf[kh], kf, S[j]);
      }
    }

    float p[4][4];
    if (kbase + 63 > q0w) {
      for (int j = 0; j < 4; j++) {
        int key = kbase + j*16 + l15;
        for (int r = 0; r < 4; r++) {
          int row = q0w + quad*4 + r;
          p[j][r] = (key <= row) ? __builtin_amdgcn_exp2f(S[j][r]*c2) : 0.f;
        }
      }
    } else {
      for (int j = 0; j < 4; j++)
        for (int r = 0; r < 4; r++)
          p[j][r] = __builtin_amdgcn_exp2f(S[j][r]*c2);
    }
    for (int j = 0; j < 4; j++)
      for (int r = 0; r < 4; r++) lsum[r] += p[j][r];

    for (int j = 0; j < 4; j++) {
      int cblk = j*2 + (l15 >> 3);
      int koff = l15 & 7;
      for (int r = 0; r < 4; r++) {
        int q = quad*4 + r;
        Pw[q*64 + (cblk ^ (q & 7))*8 + koff] = __float2bfloat16(p[j][r]);
      }
    }

    for (int kh = 0; kh < 2; kh++) {
      bf16x8 pf = *reinterpret_cast<const bf16x8*>(
          Pw + l15*64 + ((kh*4 + quad) ^ (l15 & 7))*8);
      for (int j = 0; j < 4; j++) {
        int d = j*16 + l15;
        bf16x8 vf = *reinterpret_cast<const bf16x8*>(
            Vs + d*64 + ((kh*4 + quad) ^ (d & 7))*8);
        O[j] = MFMA16(pf, vf, O[j]);
      }
    }

    for (int rep = 0; rep < 2; rep++) { kreg[rep] = kreg2[rep]; vreg[rep] = vreg2[rep]; }
  }

  for (int r = 0; r < 4; r++)
    for (int msk = 1; msk < 16; msk <<= 1)
      lsum[r] += __shfl_xor(lsum[r], msk);

  // packed-A write of ctx: m = global row, k = h*64 + j*16 + l15
  for (int r = 0; r < 4; r++) {
    float inv = 1.f / lsum[r];
    int m = b*TT + q0w + quad*4 + r;
    for (int j = 0; j < 4; j++)
      packed_store(ctx, m, h*64 + j*16 + l15, CC/32,
                   __float2bfloat16(O[j][r]*inv));
  }
}

extern "C" void kernel_launch(void* const* d_in, const int* in_sizes, int n_in,
                              void* d_out, int out_size, void* d_ws, size_t ws_size,
                              hipStream_t stream)
{
  const float* x    = (const float*)d_in[0];
  const float* ln1s = (const float*)d_in[2];
  const float* ln1b = (const float*)d_in[3];
  const float* wqkv = (const float*)d_in[4];
  const float* bqkv = (const float*)d_in[5];
  const float* wap  = (const float*)d_in[6];
  const float* bap  = (const float*)d_in[7];
  const float* ln2s = (const float*)d_in[8];
  const float* ln2b = (const float*)d_in[9];
  const float* wfc  = (const float*)d_in[10];
  const float* bfc  = (const float*)d_in[11];
  const float* wmp  = (const float*)d_in[12];
  const float* bmp  = (const float*)d_in[13];

  char* ws = (char*)d_ws;
  bf16* wqkv_t = (bf16*)ws; ws += (size_t)2304*768*2;
  bf16* wap_t  = (bf16*)ws; ws += (size_t)768*768*2;
  bf16* wfc_t  = (bf16*)ws; ws += (size_t)3072*768*2;
  bf16* wmp_t  = (bf16*)ws; ws += (size_t)768*3072*2;
  bf16* buf1   = (bf16*)ws; ws += (size_t)MROWS*CC*2;   // packed: h / ctx / h2
  bf16* Qb     = (bf16*)ws; ws += (size_t)MROWS*CC*2;
  bf16* Kbuf   = (bf16*)ws; ws += (size_t)MROWS*CC*2;
  bf16* Vb     = (bf16*)ws; ws += (size_t)MROWS*CC*2;
  bf16* Vt     = (bf16*)ws; ws += (size_t)MROWS*CC*2;
  bf16* g      = Qb;  // reuse Q/K/V/Vt region for packed [8192][3072] bf16
  float* r1    = (float*)ws; ws += (size_t)MROWS*CC*4;

  dim3 blk(256);
  // weight packs (fragment-major)
  wpack_kernel<<<dim3(2304/16, 768/128), blk, 0, stream>>>(wqkv, wqkv_t, 768, 2304);
  wpack_kernel<<<dim3(768/16, 768/128), blk, 0, stream>>>(wap, wap_t, 768, 768);
  wpack_kernel<<<dim3(3072/16, 768/128), blk, 0, stream>>>(wfc, wfc_t, 768, 3072);
  wpack_kernel<<<dim3(768/16, 3072/128), blk, 0, stream>>>(wmp, wmp_t, 3072, 768);
  // LN1 -> packed h
  ln_pack_kernel<<<MROWS, blk, 0, stream>>>(x, ln1s, ln1b, buf1);
  // QKV GEMM -> Q,K,V row-major [B,H,T,64]
  gemm_pk<0><<<dim3(2304/128, MROWS/256), blk, 0, stream>>>(
      buf1, wqkv_t, bqkv, 2304, 768, nullptr, (void*)Qb, Kbuf, Vb);
  vtrans_kernel<<<BB*HH*16, blk, 0, stream>>>(Vb, Vt);
  // attention -> packed ctx
  attn_kernel<<<BB*HH*16, blk, 0, stream>>>(Qb, Kbuf, Vt, buf1);
  // attn proj + residual -> r1 (f32 row-major)
  gemm_pk<1><<<dim3(768/128, MROWS/256), blk, 0, stream>>>(
      buf1, wap_t, bap, 768, 768, x, (void*)r1, nullptr, nullptr);
  // LN2 -> packed h2
  ln_pack_kernel<<<MROWS, blk, 0, stream>>>(r1, ln2s, ln2b, buf1);
  // fc + gelu -> packed g
  gemm_pk<2><<<dim3(3072/128, MROWS/256), blk, 0, stream>>>(
      buf1, wfc_t, bfc, 3072, 768, nullptr, (void*)g, nullptr, nullptr);
  // mlp proj + residual -> out (f32 row-major)
  gemm_pk<1><<<dim3(768/128, MROWS/256), blk, 0, stream>>>(
      g, wmp_t, bmp, 768, 3072, r1, d_out, nullptr, nullptr);
}